// Round 12
// baseline (24651.970 us; speedup 1.0000x reference)
//
#include <hip/hip_runtime.h>

typedef __bf16 bf16;
typedef __bf16 bf16x8 __attribute__((ext_vector_type(8)));
typedef __bf16 bf16x4 __attribute__((ext_vector_type(4)));
typedef float f32x4 __attribute__((ext_vector_type(4)));
typedef unsigned long long u64;

#define SCOPE_AGENT __HIP_MEMORY_SCOPE_AGENT

// B=32, T=256, H=1024, HY=256, E=64, L=2
// d_out = h_seq (32,256,1024) ++ h_last (32,1024) ++ c_last (32,1024), fp32
//
// Round 12 = Round 11 (dedicated hyper blocks, grid 288) + __launch_bounds__(256,2).
//  - Round 11 hung: 288 persistent blocks need 32 CUs hosting 2 blocks; that
//    requires VGPR <= 256 (2 waves/SIMD). The merged kernel likely allocated
//    >256 VGPR -> blocks 256..287 never scheduled -> deadlock. The (256,2)
//    bound caps VGPR at 256, guaranteeing 2-blocks/CU schedulability
//    (LDS 2x41,472 = 82,944 < 160K).
//  - Design unchanged from round 11: 32 dedicated hyper blocks take the hyper
//    role off the BC critical path (R6's straggler blocks did hyper+BC
//    serially = 1.36MB streaming = the 76us step).

__device__ __forceinline__ float sigf(float x) { return 1.0f / (1.0f + __expf(-x)); }
__device__ __forceinline__ float tanhf_fast(float x) {
  float e = __expf(-2.0f * fabsf(x));
  float r = (1.0f - e) / (1.0f + e);
  return copysignf(r, x);
}
__device__ __forceinline__ f32x4 mfma16(bf16x8 a, bf16x8 b, f32x4 c) {
  return __builtin_amdgcn_mfma_f32_16x16x32_bf16(a, b, c, 0, 0, 0);
}
// Agent-scope (MALL-coherent) primitives: NO fences -> no buffer_wbl2/buffer_inv.
__device__ __forceinline__ u64 uld(const u64* p) { return __hip_atomic_load(p, __ATOMIC_RELAXED, SCOPE_AGENT); }
__device__ __forceinline__ void ust(u64* p, u64 v) { __hip_atomic_store(p, v, __ATOMIC_RELAXED, SCOPE_AGENT); }
__device__ __forceinline__ int ildi(const int* p) { return __hip_atomic_load(p, __ATOMIC_RELAXED, SCOPE_AGENT); }
__device__ __forceinline__ void isti(int* p, int v) { __hip_atomic_store(p, v, __ATOMIC_RELAXED, SCOPE_AGENT); }
__device__ __forceinline__ void fstf(float* p, float v) { __hip_atomic_store(p, v, __ATOMIC_RELAXED, SCOPE_AGENT); }
__device__ __forceinline__ void usti32(unsigned* p, unsigned v) { __hip_atomic_store(p, v, __ATOMIC_RELAXED, SCOPE_AGENT); }

// ---------------- dtype detector ----------------
__global__ void detect_kernel(const void* probe, int* flag) {
  __shared__ int cnt;
  if (threadIdx.x == 0) cnt = 0;
  __syncthreads();
  const bf16* p = (const bf16*)probe;
  int local = 0;
  for (int j = threadIdx.x; j < 8192; j += 256) {
    float x = (float)p[j];
    bool wild = (x != x) || (fabsf(x) > 1e3f) || (x != 0.0f && fabsf(x) < 1e-30f);
    local += wild ? 1 : 0;
  }
  atomicAdd(&cnt, local);
  __syncthreads();
  if (threadIdx.x == 0) *flag = (cnt > 64) ? 1 : 0;
}

// ---------------- convert 15 tensors to canonical bf16 ----------------
struct CvtSrc { const void* s[15]; };
struct CvtDst { bf16* d[15]; };

__global__ __launch_bounds__(256) void convert_kernel(CvtSrc S, CvtDst D, const int* flag) {
  const int pre[16] = {0, 8388608, 16777216, 25165824, 29360128, 29884416, 29886464,
                       30017536, 30018048, 30149120, 30149632, 30280704, 30804992,
                       31329280, 31853568, 31861760};
  const int fp32 = *flag;
  const int nvec = 31861760 / 4;
  for (int v = blockIdx.x * 256 + threadIdx.x; v < nvec; v += gridDim.x * 256) {
    int e = v * 4;
    int seg = 0;
#pragma unroll
    for (int k = 1; k < 15; ++k) seg += (e >= pre[k]) ? 1 : 0;
    int off = e - pre[seg];
    bf16* d = D.d[seg] + off;
    if (fp32) {
      const float* s = (const float*)S.s[seg] + off;
      float4 x = *(const float4*)s;
      d[0] = (bf16)x.x; d[1] = (bf16)x.y; d[2] = (bf16)x.z; d[3] = (bf16)x.w;
    } else {
      const bf16* s = (const bf16*)S.s[seg] + off;
      d[0] = s[0]; d[1] = s[1]; d[2] = s[2]; d[3] = s[3];
    }
  }
}

// ---------------- init: zero publish buffers + flags ----------------
// 360,448 B = 45,056 u64 -> 176 blocks x 256 threads.
__global__ void init_kernel(u64* zbase) {
  int i = blockIdx.x * 256 + threadIdx.x;
  zbase[i] = 0ull;
}

// ---------------- precompute GEMM (layer 0 only) ----------------
__global__ __launch_bounds__(256) void gemm_pre(
    const bf16* __restrict__ A, const bf16* __restrict__ w_ih_l,
    const bf16* __restrict__ hwih_l, bf16* __restrict__ Xp, float* __restrict__ Hxp) {
  constexpr int LDT = 72;
  __shared__ alignas(16) bf16 As[64 * LDT];
  __shared__ alignas(16) bf16 Bs[64 * LDT];
  const int bm = blockIdx.x & 127;
  const int bn = blockIdx.x >> 7;
  const int m0 = bm * 64, n0 = bn * 64;
  const int tid = threadIdx.x;
  const int lane = tid & 63, wid = tid >> 6;
  const int l15 = lane & 15, q = lane >> 4;
  const int srow = tid >> 2, sk = (tid & 3) * 16;
  const bf16* arow = A + (size_t)(m0 + srow) * 1024;
  const int n = n0 + srow;
  const bf16* brow = (n < 4096) ? (w_ih_l + (size_t)n * 1024)
                                : (hwih_l + (size_t)(n - 4096) * 2048);
  f32x4 acc[4] = {};
  for (int kb = 0; kb < 1024; kb += 64) {
    *(bf16x8*)(&As[srow * LDT + sk])     = *(const bf16x8*)(arow + kb + sk);
    *(bf16x8*)(&As[srow * LDT + sk + 8]) = *(const bf16x8*)(arow + kb + sk + 8);
    *(bf16x8*)(&Bs[srow * LDT + sk])     = *(const bf16x8*)(brow + kb + sk);
    *(bf16x8*)(&Bs[srow * LDT + sk + 8]) = *(const bf16x8*)(brow + kb + sk + 8);
    __syncthreads();
#pragma unroll
    for (int kk = 0; kk < 64; kk += 32) {
      bf16x8 av = *(const bf16x8*)(&As[(wid * 16 + l15) * LDT + kk + q * 8]);
#pragma unroll
      for (int j = 0; j < 4; ++j) {
        bf16x8 bv = *(const bf16x8*)(&Bs[(j * 16 + l15) * LDT + kk + q * 8]);
        acc[j] = mfma16(av, bv, acc[j]);
      }
    }
    __syncthreads();
  }
#pragma unroll
  for (int j = 0; j < 4; ++j) {
    const int gn = n0 + j * 16 + l15;
#pragma unroll
    for (int r = 0; r < 4; ++r) {
      const int gm = m0 + wid * 16 + q * 4 + r;
      float v = acc[j][r];
      if (gn < 4096) Xp[(size_t)gm * 4096 + gn] = (bf16)v;
      else           Hxp[(size_t)gm * 1024 + (gn - 4096)] = v;
    }
  }
}

struct SeqArgs {
  const bf16 *w_hh, *hwih, *hwhh, *hyb;
  const bf16 *w_zh, *b_zh, *w_zx, *b_zx, *w_zb;
  const bf16 *w_dh, *w_dx, *w_db, *b0;
  const bf16 *Xp; const float *Hxp;   // layer-0 precomputed (clean memory)
  const bf16 *w_ih1;                  // layer-1 input weights (chunk GEMM)
  bf16 *Xp1c; float *Hxp1c;           // layer-1 chunk buffers (agent-scope)
  u64 *Y0;                            // layer-0 hidden seq (bf16 packed u64)
  u64 *hpub;                          // [layer][2 parity][8192]
  u64 *hh2pub;                        // [layer][2 parity][2048]
  float *outp;
  int *flags;
};

// ---------------- persistent pipelined kernel ----------------
// 288 blocks x 256 thr, __launch_bounds__(256,2) -> VGPR<=256 -> 2 blocks/CU
// schedulable. blk<256: BC (round-6 map). blk>=256: dedicated hyper.
// Flags(int): genp0@0 genp1@16 gchunk@32 arr@64+layer*2048
// hh2f@4160+layer*256 carr@4672.
__global__ __launch_bounds__(256, 2) void seq_kernel(SeqArgs a) {
  __shared__ char smem[41472] __attribute__((aligned(16)));
  // hyper-role arrays
  bf16 (*hstage)[1032] = (bf16(*)[1032])smem;           // 16x1032 bf16 = 33024
  bf16 (*hhK)[264]    = (bf16(*)[264])(smem + 33024);   // 16x264 bf16 = 8448
  float* hgL          = (float*)(smem + 33024);         // overlay: 4*16*32*4 = 8192
  // BC-role arrays
  bf16 (*hA4)[1032]   = (bf16(*)[1032])smem;           // 8256
  bf16 (*hh2A)[264]   = (bf16(*)[264])(smem + 8256);   // 2112
  float (*RhL)[256]   = (float(*)[256])(smem + 10368); // 4096
  float (*zsL)[768]   = (float(*)[768])(smem + 14464); // 12288
  float (*presL)[256] = (float(*)[256])(smem + 26752); // 4096
  bf16 (*hbuf)[64]    = (bf16(*)[64])(smem + 30848);   // 512
  // chunk-GEMM views (time-share, barrier-separated)
  bf16*  As = (bf16*)smem;               // 9216
  bf16*  Bs = (bf16*)(smem + 9216);      // 9216
  float* Ct = (float*)(smem + 18432);    // 16384 -> 34816

  const int tid = threadIdx.x;
  const int lane = tid & 63, wid = tid >> 6;
  const int l15 = lane & 15, q = lane >> 4;
  const int blk = blockIdx.x;

  // ==================== dedicated hyper blocks ====================
  if (blk >= 256) {
    const int idx = blk - 256;
    const int xcd = idx & 7;
    const int layer = xcd >> 2, xl = xcd & 3;
    const int hj = xl * 4 + (idx >> 3);
    const int hd = hj >> 1, mh = hj & 1;

    u64* hbase  = a.hpub + (size_t)layer * 16384;
    u64* h2base = a.hh2pub + (size_t)layer * 4096;
    int* genp   = a.flags + layer * 16;
    int* gchunkp= a.flags + 32;
    int* hh2fp  = a.flags + 4160 + layer * 256;
    const bf16* hybl = a.hyb + layer * 1024;

    float hc[2] = {0, 0};
    const bf16* hirow[2];
    const bf16* hhrow[2];
#pragma unroll
    for (int nt = 0; nt < 2; ++nt) {
      const int row = wid * 256 + hd * 32 + nt * 16 + l15;
      hirow[nt] = a.hwih + (size_t)layer * 2097152 + (size_t)row * 2048 + 1024;
      hhrow[nt] = a.hwhh + (size_t)layer * 262144 + (size_t)row * 256;
    }

    for (int t = 0; t < 256; ++t) {
      const int tloc = t & 31;
      const u64* rslot = hbase + (size_t)((t + 1) & 1) * 8192;  // h(t-1)
      u64* wcur = h2base + (size_t)(t & 1) * 2048;              // hh2(t) out
      const u64* rK = h2base + (size_t)((t + 1) & 1) * 2048;    // hh2(t-1)

      if (t > 0 && tid == 0) {
        while (ildi(genp) < t) __builtin_amdgcn_s_sleep(2);
      }
      if (layer == 1 && tloc == 0 && tid == 64) {   // Hxp1c chunk ready
        while (ildi(gchunkp) < (t >> 5) + 1) __builtin_amdgcn_s_sleep(2);
      }
      __atomic_signal_fence(__ATOMIC_SEQ_CST);
      __syncthreads();

      // stage h(t-1) for my 16 batches + hh2(t-1) for my 16 batches
      for (int i = tid; i < 4096; i += 256) {
        int b = i >> 8, u = i & 255;
        *(u64*)&hstage[b][u * 4] = uld(rslot + ((size_t)(mh * 16 + b) << 8) + u);
      }
      for (int i = tid; i < 1024; i += 256) {
        int b = i >> 6, u = i & 63;
        *(u64*)&hhK[b][u * 4] = uld(rK + ((size_t)(mh * 16 + b) << 6) + u);
      }
      __syncthreads();
      f32x4 acc[2] = {};
      for (int kk = 0; kk < 1024; kk += 32) {
        int ko = kk + q * 8;
        bf16x8 a0 = *(const bf16x8*)&hstage[l15][ko];
#pragma unroll
        for (int nt = 0; nt < 2; ++nt) {
          bf16x8 bv = *(const bf16x8*)(hirow[nt] + ko);
          acc[nt] = mfma16(a0, bv, acc[nt]);
        }
      }
      for (int kk = 0; kk < 256; kk += 32) {
        int ko = kk + q * 8;
        bf16x8 a0 = *(const bf16x8*)&hhK[l15][ko];
#pragma unroll
        for (int nt = 0; nt < 2; ++nt) {
          bf16x8 bv = *(const bf16x8*)(hhrow[nt] + ko);
          acc[nt] = mfma16(a0, bv, acc[nt]);
        }
      }
      __syncthreads();     // hhK reads done before hgL overlay writes
#pragma unroll
      for (int nt = 0; nt < 2; ++nt)
#pragma unroll
        for (int r = 0; r < 4; ++r)
          hgL[(wid * 16 + q * 4 + r) * 32 + nt * 16 + l15] = acc[nt][r];
      __syncthreads();
      // hyper cell for (b16, d0..d0+1); hc owned exclusively here
      {
        const int b16 = tid >> 4, d0 = (tid & 15) * 2;
        const int b = mh * 16 + b16;
        float hx2[4][2];
        if (layer == 0) {
          const float* hx = a.Hxp + ((size_t)b * 256 + t) * 1024 + hd * 32 + d0;
#pragma unroll
          for (int g = 0; g < 4; ++g) {
            hx2[g][0] = hx[g * 256]; hx2[g][1] = hx[g * 256 + 1];
          }
        } else {
          const u64* hx1 = (const u64*)a.Hxp1c + (((size_t)b * 32 + tloc) << 9)
                         + ((hd * 32 + d0) >> 1);
#pragma unroll
          for (int g = 0; g < 4; ++g) {
            u64 w = uld(hx1 + g * 128);
            hx2[g][0] = __uint_as_float((unsigned)(w & 0xffffffffu));
            hx2[g][1] = __uint_as_float((unsigned)(w >> 32));
          }
        }
        union { bf16 h[2]; unsigned u; } pk;
#pragma unroll
        for (int dd = 0; dd < 2; ++dd) {
          int d = d0 + dd, gd = hd * 32 + d;
          float hi  = hgL[(0 * 16 + b16) * 32 + d] + (float)hybl[gd]       + hx2[0][dd];
          float hf  = hgL[(1 * 16 + b16) * 32 + d] + (float)hybl[256 + gd] + hx2[1][dd];
          float hgv = hgL[(2 * 16 + b16) * 32 + d] + (float)hybl[512 + gd] + hx2[2][dd];
          float ho  = hgL[(3 * 16 + b16) * 32 + d] + (float)hybl[768 + gd] + hx2[3][dd];
          hc[dd] = sigf(hf) * hc[dd] + sigf(hi) * tanhf_fast(hgv);
          pk.h[dd] = (bf16)(sigf(ho) * tanhf_fast(hc[dd]));
        }
        usti32((unsigned*)wcur + b * 128 + hd * 16 + (d0 >> 1), pk.u);
      }
      __atomic_signal_fence(__ATOMIC_SEQ_CST);
      __builtin_amdgcn_s_waitcnt(0);
      __syncthreads();
      if (tid == 0) isti(hh2fp + (hd * 2 + mh) * 16, t + 1);
    }
    return;
  }

  // ==================== BC blocks (round 6 minus hyper role) ====================
  const int xcd = blk & 7, slot = blk >> 3;
  const int layer = xcd >> 2, xl = xcd & 3;
  const int s16 = xl * 4 + (slot & 3);
  const int bq = slot >> 2;
  const int lblk = bq * 16 + s16;

  u64* hbase  = a.hpub + (size_t)layer * 16384;
  u64* h2base = a.hh2pub + (size_t)layer * 4096;
  int* genp0  = a.flags;
  int* genp   = a.flags + layer * 16;
  int* gchunkp= a.flags + 32;
  int* arrp   = a.flags + 64 + layer * 2048;
  int* hh2fp  = a.flags + 4160 + layer * 256;
  int* carrp  = a.flags + 4672;

  const bf16* whh_l = a.w_hh + (size_t)layer * 4194304;
  const bf16* bzh_l = a.b_zh + layer * 256;
  const bf16* bzx_l = a.b_zx + layer * 256;
  const bf16* b0_l  = a.b0 + (size_t)layer * 4096;
  const int cb = tid >> 6, chl = tid & 63;

  float c_reg = 0.0f;        // main c -- block-private

  const bf16* zrow[12];
#pragma unroll
  for (int j = 0; j < 12; ++j) {
    int ng = wid * 12 + j, tau = ng >> 4;
    const bf16* base = (tau == 0) ? a.w_zh : (tau == 1) ? a.w_zx : a.w_zb;
    zrow[j] = base + ((size_t)layer * 256 + (ng & 15) * 16 + l15) * 256;
  }
  const bf16* rrow[4];
#pragma unroll
  for (int nt = 0; nt < 4; ++nt)
    rrow[nt] = whh_l + (size_t)(wid * 1024 + s16 * 64 + nt * 16 + l15) * 1024;
  const size_t wdo = ((size_t)(layer * 4 + wid) * 1024 + s16 * 64 + lane) * 64;
  const bf16 *pdh = a.w_dh + wdo, *pdx = a.w_dx + wdo, *pdb = a.w_db + wdo;

  for (int t = 0; t < 256; ++t) {
    const int tloc = t & 31;
    u64* wslot = hbase + (size_t)(t & 1) * 8192;              // h(t) out
    const u64* rslot = hbase + (size_t)((t + 1) & 1) * 8192;  // h(t-1) in
    u64* wcur = h2base + (size_t)(t & 1) * 2048;              // hh2(t) in

    // ================= layer-1 chunk GEMM (every 32 steps) =================
    if (layer == 1 && tloc == 0) {
      const int k = t >> 5;
      if (tid == 0) { while (ildi(genp0) < (k + 1) * 32) __builtin_amdgcn_s_sleep(2); }
      // Xp1c WAR guard: all own-layer blocks finished step t-1
      if (t > 0 && tid == 32) { while (ildi(genp) < t) __builtin_amdgcn_s_sleep(2); }
      __atomic_signal_fence(__ATOMIC_SEQ_CST);
      __syncthreads();
      const int srow = tid >> 2, sk = (tid & 3) * 16;
      for (int tt = 0; tt < 10; ++tt) {
        const int tile = lblk * 10 + tt;          // 1280 tiles = 16 m x 80 n
        const int m0 = (tile & 15) * 64, n0 = (tile >> 4) * 64;
        const int m = m0 + srow;
        const u64* arow = a.Y0 + (((size_t)(m >> 5) * 256 + k * 32 + (m & 31)) << 8);
        const int n = n0 + srow;
        const bf16* brow = (n < 4096) ? (a.w_ih1 + (size_t)n * 1024)
                                      : (a.hwih + 2097152 + (size_t)(n - 4096) * 2048);
        f32x4 acc[4] = {};
        for (int kb = 0; kb < 1024; kb += 64) {
          const int c0 = (kb + sk) >> 2;
          u64 a0 = uld(arow + c0),     a1 = uld(arow + c0 + 1);
          u64 a2 = uld(arow + c0 + 2), a3 = uld(arow + c0 + 3);
          *(u64*)&As[srow * 72 + sk]      = a0;
          *(u64*)&As[srow * 72 + sk + 4]  = a1;
          *(u64*)&As[srow * 72 + sk + 8]  = a2;
          *(u64*)&As[srow * 72 + sk + 12] = a3;
          *(bf16x8*)&Bs[srow * 72 + sk]     = *(const bf16x8*)(brow + kb + sk);
          *(bf16x8*)&Bs[srow * 72 + sk + 8] = *(const bf16x8*)(brow + kb + sk + 8);
          __syncthreads();
#pragma unroll
          for (int kk = 0; kk < 64; kk += 32) {
            bf16x8 av = *(const bf16x8*)&As[(wid * 16 + l15) * 72 + kk + q * 8];
#pragma unroll
            for (int j = 0; j < 4; ++j) {
              bf16x8 bv = *(const bf16x8*)&Bs[(j * 16 + l15) * 72 + kk + q * 8];
              acc[j] = mfma16(av, bv, acc[j]);
            }
          }
          __syncthreads();
        }
#pragma unroll
        for (int j = 0; j < 4; ++j)
#pragma unroll
          for (int r = 0; r < 4; ++r)
            Ct[(wid * 16 + q * 4 + r) * 64 + j * 16 + l15] = acc[j][r];
        __syncthreads();
#pragma unroll
        for (int e = 0; e < 4; ++e) {
          const int qd = tid * 4 + e;
          const int row = qd >> 4, col4 = (qd & 15) * 4;
          f32x4 v = *(const f32x4*)&Ct[row * 64 + col4];
          const int gm = m0 + row, gn = n0 + col4;
          if (gn < 4096) {
            union { bf16 h[4]; u64 u; } pk;
#pragma unroll
            for (int x = 0; x < 4; ++x) pk.h[x] = (bf16)v[x];
            ust((u64*)a.Xp1c + ((((size_t)gm << 12) + gn) >> 2), pk.u);
          } else {
            float* hp = a.Hxp1c + ((size_t)gm << 10) + (gn - 4096);
#pragma unroll
            for (int x = 0; x < 4; ++x) fstf(hp + x, v[x]);
          }
        }
        __syncthreads();
      }
      __atomic_signal_fence(__ATOMIC_SEQ_CST);
      __builtin_amdgcn_s_waitcnt(0);
      __syncthreads();
      if (tid == 0) isti(carrp + lblk * 16, k + 1);
      if (lblk == 0 && wid == 0) {
        for (;;) {
          int v0 = ildi(carrp + lane * 32);
          int v1 = ildi(carrp + lane * 32 + 16);
          if (__all((v0 >= k + 1) && (v1 >= k + 1))) break;
          __builtin_amdgcn_s_sleep(2);
        }
        __atomic_signal_fence(__ATOMIC_SEQ_CST);
        if (lane == 0) isti(gchunkp, k + 1);
      }
      if (tid == 0) { while (ildi(gchunkp) < k + 1) __builtin_amdgcn_s_sleep(2); }
      __atomic_signal_fence(__ATOMIC_SEQ_CST);
      __syncthreads();
    }

    // ================= per-step wait (own-layer master gen) =================
    if (t > 0 && tid == 0) {
      while (ildi(genp) < t) __builtin_amdgcn_s_sleep(2);
    }
    __atomic_signal_fence(__ATOMIC_SEQ_CST);
    __syncthreads();

    // ---- BC: stage own 4 batches of h(t-1) ----
    for (int i = tid; i < 1024; i += 256) {
      int b = i >> 8, u = i & 255;
      *(u64*)&hA4[b][u * 4] = uld(rslot + ((size_t)(bq * 4 + b) << 8) + u);
    }
    __syncthreads();
    // ---- own-Rh (M=4): Rh[4b][256n] = h_own @ w_hh_slice^T ----
    {
      f32x4 racc[4] = {};
      for (int kk = 0; kk < 1024; kk += 32) {
        const int ko = kk + q * 8;
        bf16x8 av = *(const bf16x8*)&hA4[l15 & 3][ko];
#pragma unroll
        for (int nt = 0; nt < 4; ++nt) {
          bf16x8 bv = *(const bf16x8*)(rrow[nt] + ko);
          racc[nt] = mfma16(av, bv, racc[nt]);
        }
      }
      if (lane < 16) {
#pragma unroll
        for (int nt = 0; nt < 4; ++nt)
#pragma unroll
          for (int r = 0; r < 4; ++r)
            RhL[r][wid * 64 + nt * 16 + lane] = racc[nt][r];
      }
    }
    // ---- wait for hh2(t), stage own 4 batches (1 uld/thread) ----
    if (tid < 16) { while (ildi(hh2fp + tid * 16) < t + 1) __builtin_amdgcn_s_sleep(1); }
    __atomic_signal_fence(__ATOMIC_SEQ_CST);
    __syncthreads();
    {
      int b = tid >> 6, u = tid & 63;
      *(u64*)&hh2A[b][u * 4] = uld(wcur + ((size_t)(bq * 4 + b) << 6) + u);
    }
    __syncthreads();
    // ---- z = hh2 @ wz^T (+bias), M=4 MFMA over 3x256 outputs ----
    {
      f32x4 zacc[12] = {};
      for (int kk = 0; kk < 256; kk += 32) {
        const int ko = kk + q * 8;
        bf16x8 av = *(const bf16x8*)&hh2A[l15 & 3][ko];
#pragma unroll
        for (int j = 0; j < 12; ++j) {
          bf16x8 bv = *(const bf16x8*)(zrow[j] + ko);
          zacc[j] = mfma16(av, bv, zacc[j]);
        }
      }
      if (lane < 16) {
#pragma unroll
        for (int j = 0; j < 12; ++j) {
          int ng = wid * 12 + j, tau = ng >> 4, col = (ng & 15) * 16 + lane;
          float bias = (tau == 0) ? (float)bzh_l[col] : (tau == 1) ? (float)bzx_l[col] : 0.0f;
#pragma unroll
          for (int r = 0; r < 4; ++r) zsL[r][tau * 256 + col] = zacc[j][r] + bias;
        }
      }
    }
    __syncthreads();
    // ---- d-projections + pre ----
    {
      float dH[4] = {}, dX[4] = {}, dB[4] = {};
      for (int e0 = 0; e0 < 64; e0 += 4) {
        bf16x4 wh = *(const bf16x4*)(pdh + e0);
        bf16x4 wx = *(const bf16x4*)(pdx + e0);
        bf16x4 wb = *(const bf16x4*)(pdb + e0);
        f32x4 zh_[4], zx_[4], zb_[4];
#pragma unroll
        for (int b = 0; b < 4; ++b) {
          zh_[b] = *(const f32x4*)&zsL[b][wid * 64 + e0];
          zx_[b] = *(const f32x4*)&zsL[b][256 + wid * 64 + e0];
          zb_[b] = *(const f32x4*)&zsL[b][512 + wid * 64 + e0];
        }
#pragma unroll
        for (int jj = 0; jj < 4; ++jj) {
          float whf = (float)wh[jj], wxf = (float)wx[jj], wbf = (float)wb[jj];
#pragma unroll
          for (int b = 0; b < 4; ++b) {
            dH[b] += zh_[b][jj] * whf;
            dX[b] += zx_[b][jj] * wxf;
            dB[b] += zb_[b][jj] * wbf;
          }
        }
      }
      const int n = wid * 1024 + s16 * 64 + lane;
#pragma unroll
      for (int b = 0; b < 4; ++b) {
        float rh = RhL[b][wid * 64 + lane];
        float xp;
        if (layer == 0) {
          xp = (float)a.Xp[((size_t)(bq * 4 + b) * 256 + t) * 4096 + n];
        } else {
          u64 w = uld((const u64*)a.Xp1c
                      + ((((size_t)((bq * 4 + b) * 32 + tloc) << 12) + (n & ~3)) >> 2));
          xp = __uint_as_float(((unsigned)(w >> ((n & 3) * 16)) & 0xffffu) << 16);
        }
        float b0v = (float)b0_l[n];
        presL[b][wid * 64 + lane] = dH[b] * rh + dX[b] * xp + dB[b] + b0v;
      }
    }
    __syncthreads();
    // ---- main cell + outputs ----
    {
      float iv = presL[cb][chl];
      float fv = presL[cb][64 + chl];
      float gv = presL[cb][128 + chl];
      float ov = presL[cb][192 + chl];
      c_reg = sigf(fv) * c_reg + sigf(iv) * tanhf_fast(gv);
      float hn = sigf(ov) * tanhf_fast(c_reg);
      hbuf[cb][chl] = (bf16)hn;
      if (layer) {
        const size_t oo = ((size_t)(bq * 4 + cb) * 256 + t) * 1024 + s16 * 64 + chl;
        a.outp[oo] = hn;
        if (t == 255) {
          a.outp[8388608 + (bq * 4 + cb) * 1024 + s16 * 64 + chl] = hn;
          a.outp[8421376 + (bq * 4 + cb) * 1024 + s16 * 64 + chl] = c_reg;
        }
      }
    }
    __syncthreads();
    // ---- publish own h slice to parity slot (layer 0 also -> Y0), arrive ----
    if (tid < 64) {
      int b = tid >> 4, u = tid & 15;
      u64 pk = *(const u64*)&hbuf[b][u * 4];
      ust(wslot + ((size_t)(bq * 4 + b) << 8) + s16 * 16 + u, pk);
      if (layer == 0)
        ust(a.Y0 + (((size_t)(bq * 4 + b) * 256 + t) << 8) + s16 * 16 + u, pk);
    }
    __atomic_signal_fence(__ATOMIC_SEQ_CST);
    __builtin_amdgcn_s_waitcnt(0);
    __syncthreads();
    if (tid == 0) isti(arrp + lblk * 16, t + 1);
    if (lblk == 0 && wid == 0) {   // per-layer master sweep: 64 lanes x 2 slots
      const int t1 = t + 1;
      for (;;) {
        int v0 = ildi(arrp + lane * 32);
        int v1 = ildi(arrp + lane * 32 + 16);
        if (__all((v0 >= t1) && (v1 >= t1))) break;
        __builtin_amdgcn_s_sleep(2);
      }
      __atomic_signal_fence(__ATOMIC_SEQ_CST);
      if (lane == 0) isti(genp, t1);
    }
  }
}

extern "C" void kernel_launch(void* const* d_in, const int* in_sizes, int n_in,
                              void* d_out, int out_size, void* d_ws, size_t ws_size,
                              hipStream_t stream) {
  float* outp = (float*)d_out;
  char* ws = (char*)d_ws;
  bf16*  Xp     = (bf16*) (ws);                      // 67,108,864 (layer 0)
  float* Hxp    = (float*)(ws + 67108864ull);        // 33,554,432 (layer 0)
  u64*   Y0     = (u64*)  (ws + 100663296ull);       // 16,777,216 (layer-0 h seq)
  bf16* c_input = (bf16*)(ws + 117669888ull);        // 16,777,216 (dead after gemm_pre)
  bf16*  Xp1c   = c_input;                           //  8,388,608 (chunk reuse)
  float* Hxp1c  = (float*)(ws + 117669888ull + 8388608ull); // 4,194,304
  bf16* c_w_ih  = (bf16*)(ws + 134447104ull);        // 16,777,216
  bf16* c_w_hh  = (bf16*)(ws + 151224320ull);        // 16,777,216
  bf16* c_hwih  = (bf16*)(ws + 168001536ull);        //  8,388,608
  bf16* c_hwhh  = (bf16*)(ws + 176390144ull);        //  1,048,576
  bf16* c_hyb   = (bf16*)(ws + 177438720ull);        //      4,096
  bf16* c_wzh   = (bf16*)(ws + 177442816ull);        //    262,144
  bf16* c_bzh   = (bf16*)(ws + 177704960ull);        //      1,024
  bf16* c_wzx   = (bf16*)(ws + 177705984ull);        //    262,144
  bf16* c_bzx   = (bf16*)(ws + 177968128ull);        //      1,024
  bf16* c_wzb   = (bf16*)(ws + 177969152ull);        //    262,144
  bf16* c_wdh   = (bf16*)(ws + 178231296ull);        //  1,048,576
  bf16* c_wdx   = (bf16*)(ws + 179279872ull);        //  1,048,576
  bf16* c_wdb   = (bf16*)(ws + 180328448ull);        //  1,048,576
  bf16* c_b0    = (bf16*)(ws + 181377024ull);        //     16,384
  int*  dflag   = (int*) (ws + 181393408ull);        //          4
  char* pubb    = ws + 181397504ull;                 // publish region (360,448 B)
  u64*   hpub   = (u64*)  (pubb + 0);                // 2 layer x 2 parity x 65,536
  u64*   hh2pub = (u64*)  (pubb + 262144);           // 2 layer x 2 parity x 16,384
  int*   flags  = (int*)  (pubb + 327680);           //     32,768

  hipLaunchKernelGGL(detect_kernel, dim3(1), dim3(256), 0, stream, d_in[2], dflag);
  CvtSrc S; CvtDst D;
  for (int i = 0; i < 15; ++i) S.s[i] = d_in[i];
  D.d[0] = c_input; D.d[1] = c_w_ih; D.d[2] = c_w_hh; D.d[3] = c_hwih; D.d[4] = c_hwhh;
  D.d[5] = c_hyb;   D.d[6] = c_wzh;  D.d[7] = c_bzh;  D.d[8] = c_wzx;  D.d[9] = c_bzx;
  D.d[10] = c_wzb;  D.d[11] = c_wdh; D.d[12] = c_wdx; D.d[13] = c_wdb; D.d[14] = c_b0;
  hipLaunchKernelGGL(convert_kernel, dim3(2048), dim3(256), 0, stream, S, D, dflag);

  // zero pubs + flags (360,448 B = 45,056 u64 -> 176 blocks)
  hipLaunchKernelGGL(init_kernel, dim3(176), dim3(256), 0, stream, (u64*)pubb);
  // layer-0 precompute only (layer 1's x-GEMMs run chunked inside seq_kernel)
  hipLaunchKernelGGL(gemm_pre, dim3(10240), dim3(256), 0, stream,
                     c_input, c_w_ih, c_hwih, Xp, Hxp);

  SeqArgs sa;
  sa.w_hh = c_w_hh; sa.hwih = c_hwih; sa.hwhh = c_hwhh; sa.hyb = c_hyb;
  sa.w_zh = c_wzh; sa.b_zh = c_bzh; sa.w_zx = c_wzx; sa.b_zx = c_bzx; sa.w_zb = c_wzb;
  sa.w_dh = c_wdh; sa.w_dx = c_wdx; sa.w_db = c_wdb; sa.b0 = c_b0;
  sa.Xp = Xp; sa.Hxp = Hxp;
  sa.w_ih1 = c_w_ih + (size_t)4194304;
  sa.Xp1c = Xp1c; sa.Hxp1c = Hxp1c;
  sa.Y0 = Y0;
  sa.hpub = hpub; sa.hh2pub = hh2pub;
  sa.outp = outp;
  sa.flags = flags;
  hipLaunchKernelGGL(seq_kernel, dim3(288), dim3(256), 0, stream, sa);
}

// Round 13
// 19616.573 us; speedup vs baseline: 1.2567x; 1.2567x over previous
//
#include <hip/hip_runtime.h>

typedef __bf16 bf16;
typedef __bf16 bf16x8 __attribute__((ext_vector_type(8)));
typedef __bf16 bf16x4 __attribute__((ext_vector_type(4)));
typedef float f32x4 __attribute__((ext_vector_type(4)));
typedef unsigned long long u64;

#define SCOPE_AGENT __HIP_MEMORY_SCOPE_AGENT

// B=32, T=256, H=1024, HY=256, E=64, L=2
// d_out = h_seq (32,256,1024) ++ h_last (32,1024) ++ c_last (32,1024), fp32
//
// FINAL = Round 6 (best measured: 19.79 ms), resubmitted verbatim to lock in.
//  - Two-layer software pipeline (one persistent dispatch, 256 blocks; layer 1
//    lags layer 0 by one step; layer-1 x-GEMMs chunked every 32 steps).
//  - Distributed hyper cell: 16 hyper blocks/layer own (d-slice x batch-half),
//    publish only bf16 hh2 (1KB); hg never leaves the block.
//  - Layer-per-XCD-half remap -> per-XCD weight set ~3.4MB, L2-resident
//    (FETCH 3.96 -> 1.21 GB measured).
//  - Parity-dbuf hpub/hh2pub; master/genp per-layer barrier.
//  - Rounds 7-12 tested sync topology, z/d fusion, quad-locality, 2-blocks/CU,
//    dedicated hyper blocks: all neutral or negative. Step time (~76us) is a
//    serialization floor of the cross-XCD publish->flag->stage chain, not a
//    BW (HBM 1.2%) or compute (MFMA 2.2%) roofline.

__device__ __forceinline__ float sigf(float x) { return 1.0f / (1.0f + __expf(-x)); }
__device__ __forceinline__ float tanhf_fast(float x) {
  float e = __expf(-2.0f * fabsf(x));
  float r = (1.0f - e) / (1.0f + e);
  return copysignf(r, x);
}
__device__ __forceinline__ f32x4 mfma16(bf16x8 a, bf16x8 b, f32x4 c) {
  return __builtin_amdgcn_mfma_f32_16x16x32_bf16(a, b, c, 0, 0, 0);
}
// Agent-scope (MALL-coherent) primitives: NO fences -> no buffer_wbl2/buffer_inv.
__device__ __forceinline__ u64 uld(const u64* p) { return __hip_atomic_load(p, __ATOMIC_RELAXED, SCOPE_AGENT); }
__device__ __forceinline__ void ust(u64* p, u64 v) { __hip_atomic_store(p, v, __ATOMIC_RELAXED, SCOPE_AGENT); }
__device__ __forceinline__ int ildi(const int* p) { return __hip_atomic_load(p, __ATOMIC_RELAXED, SCOPE_AGENT); }
__device__ __forceinline__ void isti(int* p, int v) { __hip_atomic_store(p, v, __ATOMIC_RELAXED, SCOPE_AGENT); }
__device__ __forceinline__ void fstf(float* p, float v) { __hip_atomic_store(p, v, __ATOMIC_RELAXED, SCOPE_AGENT); }
__device__ __forceinline__ void usti32(unsigned* p, unsigned v) { __hip_atomic_store(p, v, __ATOMIC_RELAXED, SCOPE_AGENT); }

// ---------------- dtype detector ----------------
__global__ void detect_kernel(const void* probe, int* flag) {
  __shared__ int cnt;
  if (threadIdx.x == 0) cnt = 0;
  __syncthreads();
  const bf16* p = (const bf16*)probe;
  int local = 0;
  for (int j = threadIdx.x; j < 8192; j += 256) {
    float x = (float)p[j];
    bool wild = (x != x) || (fabsf(x) > 1e3f) || (x != 0.0f && fabsf(x) < 1e-30f);
    local += wild ? 1 : 0;
  }
  atomicAdd(&cnt, local);
  __syncthreads();
  if (threadIdx.x == 0) *flag = (cnt > 64) ? 1 : 0;
}

// ---------------- convert 15 tensors to canonical bf16 ----------------
struct CvtSrc { const void* s[15]; };
struct CvtDst { bf16* d[15]; };

__global__ __launch_bounds__(256) void convert_kernel(CvtSrc S, CvtDst D, const int* flag) {
  const int pre[16] = {0, 8388608, 16777216, 25165824, 29360128, 29884416, 29886464,
                       30017536, 30018048, 30149120, 30149632, 30280704, 30804992,
                       31329280, 31853568, 31861760};
  const int fp32 = *flag;
  const int nvec = 31861760 / 4;
  for (int v = blockIdx.x * 256 + threadIdx.x; v < nvec; v += gridDim.x * 256) {
    int e = v * 4;
    int seg = 0;
#pragma unroll
    for (int k = 1; k < 15; ++k) seg += (e >= pre[k]) ? 1 : 0;
    int off = e - pre[seg];
    bf16* d = D.d[seg] + off;
    if (fp32) {
      const float* s = (const float*)S.s[seg] + off;
      float4 x = *(const float4*)s;
      d[0] = (bf16)x.x; d[1] = (bf16)x.y; d[2] = (bf16)x.z; d[3] = (bf16)x.w;
    } else {
      const bf16* s = (const bf16*)S.s[seg] + off;
      d[0] = s[0]; d[1] = s[1]; d[2] = s[2]; d[3] = s[3];
    }
  }
}

// ---------------- init: zero publish buffers + flags ----------------
// 360,448 B = 45,056 u64 -> 176 blocks x 256 threads.
__global__ void init_kernel(u64* zbase) {
  int i = blockIdx.x * 256 + threadIdx.x;
  zbase[i] = 0ull;
}

// ---------------- precompute GEMM (layer 0 only) ----------------
__global__ __launch_bounds__(256) void gemm_pre(
    const bf16* __restrict__ A, const bf16* __restrict__ w_ih_l,
    const bf16* __restrict__ hwih_l, bf16* __restrict__ Xp, float* __restrict__ Hxp) {
  constexpr int LDT = 72;
  __shared__ alignas(16) bf16 As[64 * LDT];
  __shared__ alignas(16) bf16 Bs[64 * LDT];
  const int bm = blockIdx.x & 127;
  const int bn = blockIdx.x >> 7;
  const int m0 = bm * 64, n0 = bn * 64;
  const int tid = threadIdx.x;
  const int lane = tid & 63, wid = tid >> 6;
  const int l15 = lane & 15, q = lane >> 4;
  const int srow = tid >> 2, sk = (tid & 3) * 16;
  const bf16* arow = A + (size_t)(m0 + srow) * 1024;
  const int n = n0 + srow;
  const bf16* brow = (n < 4096) ? (w_ih_l + (size_t)n * 1024)
                                : (hwih_l + (size_t)(n - 4096) * 2048);
  f32x4 acc[4] = {};
  for (int kb = 0; kb < 1024; kb += 64) {
    *(bf16x8*)(&As[srow * LDT + sk])     = *(const bf16x8*)(arow + kb + sk);
    *(bf16x8*)(&As[srow * LDT + sk + 8]) = *(const bf16x8*)(arow + kb + sk + 8);
    *(bf16x8*)(&Bs[srow * LDT + sk])     = *(const bf16x8*)(brow + kb + sk);
    *(bf16x8*)(&Bs[srow * LDT + sk + 8]) = *(const bf16x8*)(brow + kb + sk + 8);
    __syncthreads();
#pragma unroll
    for (int kk = 0; kk < 64; kk += 32) {
      bf16x8 av = *(const bf16x8*)(&As[(wid * 16 + l15) * LDT + kk + q * 8]);
#pragma unroll
      for (int j = 0; j < 4; ++j) {
        bf16x8 bv = *(const bf16x8*)(&Bs[(j * 16 + l15) * LDT + kk + q * 8]);
        acc[j] = mfma16(av, bv, acc[j]);
      }
    }
    __syncthreads();
  }
#pragma unroll
  for (int j = 0; j < 4; ++j) {
    const int gn = n0 + j * 16 + l15;
#pragma unroll
    for (int r = 0; r < 4; ++r) {
      const int gm = m0 + wid * 16 + q * 4 + r;
      float v = acc[j][r];
      if (gn < 4096) Xp[(size_t)gm * 4096 + gn] = (bf16)v;
      else           Hxp[(size_t)gm * 1024 + (gn - 4096)] = v;
    }
  }
}

struct SeqArgs {
  const bf16 *w_hh, *hwih, *hwhh, *hyb;
  const bf16 *w_zh, *b_zh, *w_zx, *b_zx, *w_zb;
  const bf16 *w_dh, *w_dx, *w_db, *b0;
  const bf16 *Xp; const float *Hxp;   // layer-0 precomputed (clean memory)
  const bf16 *w_ih1;                  // layer-1 input weights (chunk GEMM)
  bf16 *Xp1c; float *Hxp1c;           // layer-1 chunk buffers (agent-scope)
  u64 *Y0;                            // layer-0 hidden seq (bf16 packed u64)
  u64 *hpub;                          // [layer][2 parity][8192]
  u64 *hh2pub;                        // [layer][2 parity][2048]
  float *outp;
  int *flags;
};

// ---------------- persistent pipelined kernel ----------------
// 256 blocks x 256 thr. Remap: xcd=blk&7; layer=xcd>>2; xl=xcd&3; slot=blk>>3;
// s16=xl*4+(slot&3); bq=slot>>2. Hyper role: s16 even, bq==hd or (hd+4)&7
// where hd=s16>>1 (16 hyper blocks/layer; hd=d-slice, mh=batch half).
// Flags(int): genp0@0 genp1@16 gchunk@32 arr@64+layer*2048
// hh2f@4160+layer*256 carr@4672.
__global__ __launch_bounds__(256) void seq_kernel(SeqArgs a) {
  __shared__ char smem[41472] __attribute__((aligned(16)));
  // hyper-role arrays
  bf16 (*hstage)[1032] = (bf16(*)[1032])smem;           // 16x1032 bf16 = 33024
  bf16 (*hhK)[264]    = (bf16(*)[264])(smem + 33024);   // 16x264 bf16 = 8448
  float* hgL          = (float*)(smem + 33024);         // overlay: 4*16*32*4 = 8192
  // BC-role arrays (reused after hyper, barrier-separated)
  bf16 (*hA4)[1032]   = (bf16(*)[1032])smem;           // 8256
  bf16 (*hh2A)[264]   = (bf16(*)[264])(smem + 8256);   // 2112
  float (*RhL)[256]   = (float(*)[256])(smem + 10368); // 4096
  float (*zsL)[768]   = (float(*)[768])(smem + 14464); // 12288
  float (*presL)[256] = (float(*)[256])(smem + 26752); // 4096
  bf16 (*hbuf)[64]    = (bf16(*)[64])(smem + 30848);   // 512
  // chunk-GEMM views (time-share, barrier-separated)
  bf16*  As = (bf16*)smem;               // 9216
  bf16*  Bs = (bf16*)(smem + 9216);      // 9216
  float* Ct = (float*)(smem + 18432);    // 16384 -> 34816

  const int tid = threadIdx.x;
  const int lane = tid & 63, wid = tid >> 6;
  const int l15 = lane & 15, q = lane >> 4;
  const int blk = blockIdx.x;
  const int xcd = blk & 7, slot = blk >> 3;
  const int layer = xcd >> 2, xl = xcd & 3;
  const int s16 = xl * 4 + (slot & 3);
  const int bq = slot >> 2;
  const int lblk = bq * 16 + s16;
  const int hd = s16 >> 1;
  const int mh = (bq == hd) ? 0 : ((bq == ((hd + 4) & 7)) ? 1 : -1);
  const bool isHyper = (((s16 & 1) == 0) && (mh >= 0));

  u64* hbase  = a.hpub + (size_t)layer * 16384;
  u64* h2base = a.hh2pub + (size_t)layer * 4096;
  int* genp0  = a.flags;
  int* genp   = a.flags + layer * 16;
  int* gchunkp= a.flags + 32;
  int* arrp   = a.flags + 64 + layer * 2048;
  int* hh2fp  = a.flags + 4160 + layer * 256;
  int* carrp  = a.flags + 4672;

  const bf16* whh_l = a.w_hh + (size_t)layer * 4194304;
  const bf16* hybl  = a.hyb + layer * 1024;
  const bf16* bzh_l = a.b_zh + layer * 256;
  const bf16* bzx_l = a.b_zx + layer * 256;
  const bf16* b0_l  = a.b0 + (size_t)layer * 4096;
  const int cb = tid >> 6, chl = tid & 63;

  float c_reg = 0.0f;        // main c -- block-private
  float hc[2] = {0, 0};      // hyper c -- owned exclusively by hyper blocks

  const bf16* zrow[12];
#pragma unroll
  for (int j = 0; j < 12; ++j) {
    int ng = wid * 12 + j, tau = ng >> 4;
    const bf16* base = (tau == 0) ? a.w_zh : (tau == 1) ? a.w_zx : a.w_zb;
    zrow[j] = base + ((size_t)layer * 256 + (ng & 15) * 16 + l15) * 256;
  }
  const bf16* rrow[4];
#pragma unroll
  for (int nt = 0; nt < 4; ++nt)
    rrow[nt] = whh_l + (size_t)(wid * 1024 + s16 * 64 + nt * 16 + l15) * 1024;
  const bf16* hirow[2];
  const bf16* hhrow[2];
#pragma unroll
  for (int nt = 0; nt < 2; ++nt) {
    const int row = wid * 256 + hd * 32 + nt * 16 + l15;
    hirow[nt] = a.hwih + (size_t)layer * 2097152 + (size_t)row * 2048 + 1024;
    hhrow[nt] = a.hwhh + (size_t)layer * 262144 + (size_t)row * 256;
  }
  const size_t wdo = ((size_t)(layer * 4 + wid) * 1024 + s16 * 64 + lane) * 64;
  const bf16 *pdh = a.w_dh + wdo, *pdx = a.w_dx + wdo, *pdb = a.w_db + wdo;

  for (int t = 0; t < 256; ++t) {
    const int tloc = t & 31;
    u64* wslot = hbase + (size_t)(t & 1) * 8192;         // h(t) out
    const u64* rslot = hbase + (size_t)((t + 1) & 1) * 8192;  // h(t-1) in
    u64* wcur = h2base + (size_t)(t & 1) * 2048;         // hh2(t) out / BC in
    const u64* rK = h2base + (size_t)((t + 1) & 1) * 2048;    // hh2(t-1) in

    // ================= layer-1 chunk GEMM (every 32 steps) =================
    if (layer == 1 && tloc == 0) {
      const int k = t >> 5;
      if (tid == 0) { while (ildi(genp0) < (k + 1) * 32) __builtin_amdgcn_s_sleep(2); }
      __atomic_signal_fence(__ATOMIC_SEQ_CST);
      __syncthreads();
      const int srow = tid >> 2, sk = (tid & 3) * 16;
      for (int tt = 0; tt < 10; ++tt) {
        const int tile = lblk * 10 + tt;          // 1280 tiles = 16 m x 80 n
        const int m0 = (tile & 15) * 64, n0 = (tile >> 4) * 64;
        const int m = m0 + srow;
        const u64* arow = a.Y0 + (((size_t)(m >> 5) * 256 + k * 32 + (m & 31)) << 8);
        const int n = n0 + srow;
        const bf16* brow = (n < 4096) ? (a.w_ih1 + (size_t)n * 1024)
                                      : (a.hwih + 2097152 + (size_t)(n - 4096) * 2048);
        f32x4 acc[4] = {};
        for (int kb = 0; kb < 1024; kb += 64) {
          const int c0 = (kb + sk) >> 2;
          u64 a0 = uld(arow + c0),     a1 = uld(arow + c0 + 1);
          u64 a2 = uld(arow + c0 + 2), a3 = uld(arow + c0 + 3);
          *(u64*)&As[srow * 72 + sk]      = a0;
          *(u64*)&As[srow * 72 + sk + 4]  = a1;
          *(u64*)&As[srow * 72 + sk + 8]  = a2;
          *(u64*)&As[srow * 72 + sk + 12] = a3;
          *(bf16x8*)&Bs[srow * 72 + sk]     = *(const bf16x8*)(brow + kb + sk);
          *(bf16x8*)&Bs[srow * 72 + sk + 8] = *(const bf16x8*)(brow + kb + sk + 8);
          __syncthreads();
#pragma unroll
          for (int kk = 0; kk < 64; kk += 32) {
            bf16x8 av = *(const bf16x8*)&As[(wid * 16 + l15) * 72 + kk + q * 8];
#pragma unroll
            for (int j = 0; j < 4; ++j) {
              bf16x8 bv = *(const bf16x8*)&Bs[(j * 16 + l15) * 72 + kk + q * 8];
              acc[j] = mfma16(av, bv, acc[j]);
            }
          }
          __syncthreads();
        }
#pragma unroll
        for (int j = 0; j < 4; ++j)
#pragma unroll
          for (int r = 0; r < 4; ++r)
            Ct[(wid * 16 + q * 4 + r) * 64 + j * 16 + l15] = acc[j][r];
        __syncthreads();
#pragma unroll
        for (int e = 0; e < 4; ++e) {
          const int qd = tid * 4 + e;
          const int row = qd >> 4, col4 = (qd & 15) * 4;
          f32x4 v = *(const f32x4*)&Ct[row * 64 + col4];
          const int gm = m0 + row, gn = n0 + col4;
          if (gn < 4096) {
            union { bf16 h[4]; u64 u; } pk;
#pragma unroll
            for (int x = 0; x < 4; ++x) pk.h[x] = (bf16)v[x];
            ust((u64*)a.Xp1c + ((((size_t)gm << 12) + gn) >> 2), pk.u);
          } else {
            float* hp = a.Hxp1c + ((size_t)gm << 10) + (gn - 4096);
#pragma unroll
            for (int x = 0; x < 4; ++x) fstf(hp + x, v[x]);
          }
        }
        __syncthreads();
      }
      __atomic_signal_fence(__ATOMIC_SEQ_CST);
      __builtin_amdgcn_s_waitcnt(0);
      __syncthreads();
      if (tid == 0) isti(carrp + lblk * 16, k + 1);
      if (lblk == 0 && wid == 0) {
        for (;;) {
          int v0 = ildi(carrp + lane * 32);
          int v1 = ildi(carrp + lane * 32 + 16);
          if (__all((v0 >= k + 1) && (v1 >= k + 1))) break;
          __builtin_amdgcn_s_sleep(2);
        }
        __atomic_signal_fence(__ATOMIC_SEQ_CST);
        if (lane == 0) isti(gchunkp, k + 1);
      }
      if (tid == 0) { while (ildi(gchunkp) < k + 1) __builtin_amdgcn_s_sleep(2); }
      __atomic_signal_fence(__ATOMIC_SEQ_CST);
      __syncthreads();
    }

    // ================= per-step wait (own-layer master gen) =================
    if (t > 0 && tid == 0) {
      while (ildi(genp) < t) __builtin_amdgcn_s_sleep(2);
    }
    __atomic_signal_fence(__ATOMIC_SEQ_CST);
    __syncthreads();

    // ---- hyper role: own (d-slice x batch-half) of the hyper LSTM ----
    if (isHyper) {
      // stage h(t-1) for my 16 batches + hh2(t-1) for my 16 batches
      for (int i = tid; i < 4096; i += 256) {
        int b = i >> 8, u = i & 255;
        *(u64*)&hstage[b][u * 4] = uld(rslot + ((size_t)(mh * 16 + b) << 8) + u);
      }
      for (int i = tid; i < 1024; i += 256) {
        int b = i >> 6, u = i & 63;
        *(u64*)&hhK[b][u * 4] = uld(rK + ((size_t)(mh * 16 + b) << 6) + u);
      }
      __syncthreads();
      f32x4 acc[2] = {};
      for (int kk = 0; kk < 1024; kk += 32) {
        int ko = kk + q * 8;
        bf16x8 a0 = *(const bf16x8*)&hstage[l15][ko];
#pragma unroll
        for (int nt = 0; nt < 2; ++nt) {
          bf16x8 bv = *(const bf16x8*)(hirow[nt] + ko);
          acc[nt] = mfma16(a0, bv, acc[nt]);
        }
      }
      for (int kk = 0; kk < 256; kk += 32) {
        int ko = kk + q * 8;
        bf16x8 a0 = *(const bf16x8*)&hhK[l15][ko];
#pragma unroll
        for (int nt = 0; nt < 2; ++nt) {
          bf16x8 bv = *(const bf16x8*)(hhrow[nt] + ko);
          acc[nt] = mfma16(a0, bv, acc[nt]);
        }
      }
      __syncthreads();     // hhK reads done before hgL overlay writes
#pragma unroll
      for (int nt = 0; nt < 2; ++nt)
#pragma unroll
        for (int r = 0; r < 4; ++r)
          hgL[(wid * 16 + q * 4 + r) * 32 + nt * 16 + l15] = acc[nt][r];
      __syncthreads();
      // hyper cell for (b16, d0..d0+1); hc owned exclusively here
      {
        const int b16 = tid >> 4, d0 = (tid & 15) * 2;
        const int b = mh * 16 + b16;
        float hx2[4][2];
        if (layer == 0) {
          const float* hx = a.Hxp + ((size_t)b * 256 + t) * 1024 + hd * 32 + d0;
#pragma unroll
          for (int g = 0; g < 4; ++g) {
            hx2[g][0] = hx[g * 256]; hx2[g][1] = hx[g * 256 + 1];
          }
        } else {
          const u64* hx1 = (const u64*)a.Hxp1c + (((size_t)b * 32 + tloc) << 9)
                         + ((hd * 32 + d0) >> 1);
#pragma unroll
          for (int g = 0; g < 4; ++g) {
            u64 w = uld(hx1 + g * 128);
            hx2[g][0] = __uint_as_float((unsigned)(w & 0xffffffffu));
            hx2[g][1] = __uint_as_float((unsigned)(w >> 32));
          }
        }
        union { bf16 h[2]; unsigned u; } pk;
#pragma unroll
        for (int dd = 0; dd < 2; ++dd) {
          int d = d0 + dd, gd = hd * 32 + d;
          float hi  = hgL[(0 * 16 + b16) * 32 + d] + (float)hybl[gd]       + hx2[0][dd];
          float hf  = hgL[(1 * 16 + b16) * 32 + d] + (float)hybl[256 + gd] + hx2[1][dd];
          float hgv = hgL[(2 * 16 + b16) * 32 + d] + (float)hybl[512 + gd] + hx2[2][dd];
          float ho  = hgL[(3 * 16 + b16) * 32 + d] + (float)hybl[768 + gd] + hx2[3][dd];
          hc[dd] = sigf(hf) * hc[dd] + sigf(hi) * tanhf_fast(hgv);
          pk.h[dd] = (bf16)(sigf(ho) * tanhf_fast(hc[dd]));
        }
        usti32((unsigned*)wcur + b * 128 + hd * 16 + (d0 >> 1), pk.u);
      }
      __atomic_signal_fence(__ATOMIC_SEQ_CST);
      __builtin_amdgcn_s_waitcnt(0);
      __syncthreads();
      if (tid == 0) isti(hh2fp + (hd * 2 + mh) * 16, t + 1);
    }
    __syncthreads();   // hyper smem dead; safe to reuse for BC arrays

    // ---- BC: stage own 4 batches of h(t-1) ----
    for (int i = tid; i < 1024; i += 256) {
      int b = i >> 8, u = i & 255;
      *(u64*)&hA4[b][u * 4] = uld(rslot + ((size_t)(bq * 4 + b) << 8) + u);
    }
    __syncthreads();
    // ---- own-Rh (M=4): Rh[4b][256n] = h_own @ w_hh_slice^T ----
    {
      f32x4 racc[4] = {};
      for (int kk = 0; kk < 1024; kk += 32) {
        const int ko = kk + q * 8;
        bf16x8 av = *(const bf16x8*)&hA4[l15 & 3][ko];
#pragma unroll
        for (int nt = 0; nt < 4; ++nt) {
          bf16x8 bv = *(const bf16x8*)(rrow[nt] + ko);
          racc[nt] = mfma16(av, bv, racc[nt]);
        }
      }
      if (lane < 16) {
#pragma unroll
        for (int nt = 0; nt < 4; ++nt)
#pragma unroll
          for (int r = 0; r < 4; ++r)
            RhL[r][wid * 64 + nt * 16 + lane] = racc[nt][r];
      }
    }
    // ---- wait for hh2(t), stage own 4 batches (1 uld/thread) ----
    if (tid < 16) { while (ildi(hh2fp + tid * 16) < t + 1) __builtin_amdgcn_s_sleep(1); }
    __atomic_signal_fence(__ATOMIC_SEQ_CST);
    __syncthreads();
    {
      int b = tid >> 6, u = tid & 63;
      *(u64*)&hh2A[b][u * 4] = uld(wcur + ((size_t)(bq * 4 + b) << 6) + u);
    }
    __syncthreads();
    // ---- z = hh2 @ wz^T (+bias), M=4 MFMA over 3x256 outputs ----
    {
      f32x4 zacc[12] = {};
      for (int kk = 0; kk < 256; kk += 32) {
        const int ko = kk + q * 8;
        bf16x8 av = *(const bf16x8*)&hh2A[l15 & 3][ko];
#pragma unroll
        for (int j = 0; j < 12; ++j) {
          bf16x8 bv = *(const bf16x8*)(zrow[j] + ko);
          zacc[j] = mfma16(av, bv, zacc[j]);
        }
      }
      if (lane < 16) {
#pragma unroll
        for (int j = 0; j < 12; ++j) {
          int ng = wid * 12 + j, tau = ng >> 4, col = (ng & 15) * 16 + lane;
          float bias = (tau == 0) ? (float)bzh_l[col] : (tau == 1) ? (float)bzx_l[col] : 0.0f;
#pragma unroll
          for (int r = 0; r < 4; ++r) zsL[r][tau * 256 + col] = zacc[j][r] + bias;
        }
      }
    }
    __syncthreads();
    // ---- d-projections + pre ----
    {
      float dH[4] = {}, dX[4] = {}, dB[4] = {};
      for (int e0 = 0; e0 < 64; e0 += 4) {
        bf16x4 wh = *(const bf16x4*)(pdh + e0);
        bf16x4 wx = *(const bf16x4*)(pdx + e0);
        bf16x4 wb = *(const bf16x4*)(pdb + e0);
        f32x4 zh_[4], zx_[4], zb_[4];
#pragma unroll
        for (int b = 0; b < 4; ++b) {
          zh_[b] = *(const f32x4*)&zsL[b][wid * 64 + e0];
          zx_[b] = *(const f32x4*)&zsL[b][256 + wid * 64 + e0];
          zb_[b] = *(const f32x4*)&zsL[b][512 + wid * 64 + e0];
        }
#pragma unroll
        for (int jj = 0; jj < 4; ++jj) {
          float whf = (float)wh[jj], wxf = (float)wx[jj], wbf = (float)wb[jj];
#pragma unroll
          for (int b = 0; b < 4; ++b) {
            dH[b] += zh_[b][jj] * whf;
            dX[b] += zx_[b][jj] * wxf;
            dB[b] += zb_[b][jj] * wbf;
          }
        }
      }
      const int n = wid * 1024 + s16 * 64 + lane;
#pragma unroll
      for (int b = 0; b < 4; ++b) {
        float rh = RhL[b][wid * 64 + lane];
        float xp;
        if (layer == 0) {
          xp = (float)a.Xp[((size_t)(bq * 4 + b) * 256 + t) * 4096 + n];
        } else {
          u64 w = uld((const u64*)a.Xp1c
                      + ((((size_t)((bq * 4 + b) * 32 + tloc) << 12) + (n & ~3)) >> 2));
          xp = __uint_as_float(((unsigned)(w >> ((n & 3) * 16)) & 0xffffu) << 16);
        }
        float b0v = (float)b0_l[n];
        presL[b][wid * 64 + lane] = dH[b] * rh + dX[b] * xp + dB[b] + b0v;
      }
    }
    __syncthreads();
    // ---- main cell + outputs ----
    {
      float iv = presL[cb][chl];
      float fv = presL[cb][64 + chl];
      float gv = presL[cb][128 + chl];
      float ov = presL[cb][192 + chl];
      c_reg = sigf(fv) * c_reg + sigf(iv) * tanhf_fast(gv);
      float hn = sigf(ov) * tanhf_fast(c_reg);
      hbuf[cb][chl] = (bf16)hn;
      if (layer) {
        const size_t oo = ((size_t)(bq * 4 + cb) * 256 + t) * 1024 + s16 * 64 + chl;
        a.outp[oo] = hn;
        if (t == 255) {
          a.outp[8388608 + (bq * 4 + cb) * 1024 + s16 * 64 + chl] = hn;
          a.outp[8421376 + (bq * 4 + cb) * 1024 + s16 * 64 + chl] = c_reg;
        }
      }
    }
    __syncthreads();
    // ---- publish own h slice to parity slot (layer 0 also -> Y0) ----
    if (tid < 64) {
      int b = tid >> 4, u = tid & 15;
      u64 pk = *(const u64*)&hbuf[b][u * 4];
      ust(wslot + ((size_t)(bq * 4 + b) << 8) + s16 * 16 + u, pk);
      if (layer == 0)
        ust(a.Y0 + (((size_t)(bq * 4 + b) * 256 + t) << 8) + s16 * 16 + u, pk);
    }
    __atomic_signal_fence(__ATOMIC_SEQ_CST);
    __builtin_amdgcn_s_waitcnt(0);
    __syncthreads();
    if (tid == 0) isti(arrp + lblk * 16, t + 1);
    if (lblk == 0 && wid == 0) {   // per-layer master sweep: 64 lanes x 2 slots
      const int t1 = t + 1;
      for (;;) {
        int v0 = ildi(arrp + lane * 32);
        int v1 = ildi(arrp + lane * 32 + 16);
        if (__all((v0 >= t1) && (v1 >= t1))) break;
        __builtin_amdgcn_s_sleep(2);
      }
      __atomic_signal_fence(__ATOMIC_SEQ_CST);
      if (lane == 0) isti(genp, t1);
    }
  }
}

extern "C" void kernel_launch(void* const* d_in, const int* in_sizes, int n_in,
                              void* d_out, int out_size, void* d_ws, size_t ws_size,
                              hipStream_t stream) {
  float* outp = (float*)d_out;
  char* ws = (char*)d_ws;
  bf16*  Xp     = (bf16*) (ws);                      // 67,108,864 (layer 0)
  float* Hxp    = (float*)(ws + 67108864ull);        // 33,554,432 (layer 0)
  u64*   Y0     = (u64*)  (ws + 100663296ull);       // 16,777,216 (layer-0 h seq)
  bf16* c_input = (bf16*)(ws + 117669888ull);        // 16,777,216 (dead after gemm_pre)
  bf16*  Xp1c   = c_input;                           //  8,388,608 (chunk reuse)
  float* Hxp1c  = (float*)(ws + 117669888ull + 8388608ull); // 4,194,304
  bf16* c_w_ih  = (bf16*)(ws + 134447104ull);        // 16,777,216
  bf16* c_w_hh  = (bf16*)(ws + 151224320ull);        // 16,777,216
  bf16* c_hwih  = (bf16*)(ws + 168001536ull);        //  8,388,608
  bf16* c_hwhh  = (bf16*)(ws + 176390144ull);        //  1,048,576
  bf16* c_hyb   = (bf16*)(ws + 177438720ull);        //      4,096
  bf16* c_wzh   = (bf16*)(ws + 177442816ull);        //    262,144
  bf16* c_bzh   = (bf16*)(ws + 177704960ull);        //      1,024
  bf16* c_wzx   = (bf16*)(ws + 177705984ull);        //    262,144
  bf16* c_bzx   = (bf16*)(ws + 177968128ull);        //      1,024
  bf16* c_wzb   = (bf16*)(ws + 177969152ull);        //    262,144
  bf16* c_wdh   = (bf16*)(ws + 178231296ull);        //  1,048,576
  bf16* c_wdx   = (bf16*)(ws + 179279872ull);        //  1,048,576
  bf16* c_wdb   = (bf16*)(ws + 180328448ull);        //  1,048,576
  bf16* c_b0    = (bf16*)(ws + 181377024ull);        //     16,384
  int*  dflag   = (int*) (ws + 181393408ull);        //          4
  char* pubb    = ws + 181397504ull;                 // publish region (360,448 B)
  u64*   hpub   = (u64*)  (pubb + 0);                // 2 layer x 2 parity x 65,536
  u64*   hh2pub = (u64*)  (pubb + 262144);           // 2 layer x 2 parity x 16,384
  int*   flags  = (int*)  (pubb + 327680);           //     32,768

  hipLaunchKernelGGL(detect_kernel, dim3(1), dim3(256), 0, stream, d_in[2], dflag);
  CvtSrc S; CvtDst D;
  for (int i = 0; i < 15; ++i) S.s[i] = d_in[i];
  D.d[0] = c_input; D.d[1] = c_w_ih; D.d[2] = c_w_hh; D.d[3] = c_hwih; D.d[4] = c_hwhh;
  D.d[5] = c_hyb;   D.d[6] = c_wzh;  D.d[7] = c_bzh;  D.d[8] = c_wzx;  D.d[9] = c_bzx;
  D.d[10] = c_wzb;  D.d[11] = c_wdh; D.d[12] = c_wdx; D.d[13] = c_wdb; D.d[14] = c_b0;
  hipLaunchKernelGGL(convert_kernel, dim3(2048), dim3(256), 0, stream, S, D, dflag);

  // zero pubs + flags (360,448 B = 45,056 u64 -> 176 blocks)
  hipLaunchKernelGGL(init_kernel, dim3(176), dim3(256), 0, stream, (u64*)pubb);
  // layer-0 precompute only (layer 1's x-GEMMs run chunked inside seq_kernel)
  hipLaunchKernelGGL(gemm_pre, dim3(10240), dim3(256), 0, stream,
                     c_input, c_w_ih, c_hwih, Xp, Hxp);

  SeqArgs sa;
  sa.w_hh = c_w_hh; sa.hwih = c_hwih; sa.hwhh = c_hwhh; sa.hyb = c_hyb;
  sa.w_zh = c_wzh; sa.b_zh = c_bzh; sa.w_zx = c_wzx; sa.b_zx = c_bzx; sa.w_zb = c_wzb;
  sa.w_dh = c_wdh; sa.w_dx = c_wdx; sa.w_db = c_wdb; sa.b0 = c_b0;
  sa.Xp = Xp; sa.Hxp = Hxp;
  sa.w_ih1 = c_w_ih + (size_t)4194304;
  sa.Xp1c = Xp1c; sa.Hxp1c = Hxp1c;
  sa.Y0 = Y0;
  sa.hpub = hpub; sa.hh2pub = hh2pub;
  sa.outp = outp;
  sa.flags = flags;
  hipLaunchKernelGGL(seq_kernel, dim3(256), dim3(256), 0, stream, sa);
}